// Round 4
// baseline (113.604 us; speedup 1.0000x reference)
//
#include <hip/hip_runtime.h>

#define NQ     12
#define DIM    4096
#define QDEPTH 8
#define T      256
#define STRIDE 20              // 16 floats + 4 pad: 16B-aligned, perfect bank spread
#define BUFSZ  (T * STRIDE)

// lane-bit gate: new = X(own) + Y(partner); C = (Xr, Xi, Yr, Yi) picked per lane side.
// M=1,2 via DPP quad_perm (VALU pipe); M=4..32 via shfl_xor (ds_bpermute).
template <int M>
__device__ __forceinline__ void lane_gate(float2 amp[16], const float4 C) {
#pragma unroll
    for (int c = 0; c < 16; ++c) {
        float pr, pi;
        if constexpr (M == 1) {
            pr = __int_as_float(__builtin_amdgcn_update_dpp(
                __float_as_int(amp[c].x), __float_as_int(amp[c].x), 0xB1, 0xF, 0xF, false));
            pi = __int_as_float(__builtin_amdgcn_update_dpp(
                __float_as_int(amp[c].y), __float_as_int(amp[c].y), 0xB1, 0xF, 0xF, false));
        } else if constexpr (M == 2) {
            pr = __int_as_float(__builtin_amdgcn_update_dpp(
                __float_as_int(amp[c].x), __float_as_int(amp[c].x), 0x4E, 0xF, 0xF, false));
            pi = __int_as_float(__builtin_amdgcn_update_dpp(
                __float_as_int(amp[c].y), __float_as_int(amp[c].y), 0x4E, 0xF, 0xF, false));
        } else {
            pr = __shfl_xor(amp[c].x, M, 64);
            pi = __shfl_xor(amp[c].y, M, 64);
        }
        const float ar = amp[c].x, ai = amp[c].y;
        amp[c].x = C.x * ar - C.y * ai + C.z * pr - C.w * pi;
        amp[c].y = C.x * ai + C.y * ar + C.z * pi + C.w * pr;
    }
}

// in-register gate on c-bit m: V0=(m00r,m00i,m01r,m01i), V1=(m11r,m11i,m10r,m10i)
__device__ __forceinline__ void reg_gate(float2 amp[16], const int m,
                                         const float4 V0, const float4 V1) {
#pragma unroll
    for (int c = 0; c < 16; ++c) {
        if (c & m) continue;
        const int c1 = c | m;
        const float a0r = amp[c].x,  a0i = amp[c].y;
        const float a1r = amp[c1].x, a1i = amp[c1].y;
        amp[c].x  = V0.x * a0r - V0.y * a0i + V0.z * a1r - V0.w * a1i;
        amp[c].y  = V0.x * a0i + V0.y * a0r + V0.z * a1i + V0.w * a1r;
        amp[c1].x = V1.z * a0r - V1.w * a0i + V1.x * a1r - V1.y * a1i;
        amp[c1].y = V1.z * a0i + V1.w * a0r + V1.x * a1i + V1.y * a1r;
    }
}

// wave-bit gate: write own 16 amps (SoA b128), barrier, read partner's 16, combine
__device__ __forceinline__ void xchg_gate(float2 amp[16], float* __restrict__ bufR,
                                          float* __restrict__ bufI, const int tid,
                                          const int pmask, const float4 C) {
    float4* wr = (float4*)(bufR + STRIDE * tid);
    float4* wi = (float4*)(bufI + STRIDE * tid);
#pragma unroll
    for (int k = 0; k < 4; ++k) {
        wr[k] = make_float4(amp[4*k].x, amp[4*k+1].x, amp[4*k+2].x, amp[4*k+3].x);
        wi[k] = make_float4(amp[4*k].y, amp[4*k+1].y, amp[4*k+2].y, amp[4*k+3].y);
    }
    __syncthreads();
    const int p = tid ^ pmask;
    const float4* rr = (const float4*)(bufR + STRIDE * p);
    const float4* ri = (const float4*)(bufI + STRIDE * p);
#pragma unroll
    for (int k = 0; k < 4; ++k) {
        const float4 r4 = rr[k], i4 = ri[k];
        const float prr[4] = {r4.x, r4.y, r4.z, r4.w};
        const float pii[4] = {i4.x, i4.y, i4.z, i4.w};
#pragma unroll
        for (int j = 0; j < 4; ++j) {
            const int c = 4 * k + j;
            const float ar = amp[c].x, ai = amp[c].y;
            amp[c].x = C.x * ar - C.y * ai + C.z * prr[j] - C.w * pii[j];
            amp[c].y = C.x * ai + C.y * ar + C.z * pii[j] + C.w * prr[j];
        }
    }
}

__global__ __launch_bounds__(T) void qnn_sim(const float* __restrict__ qw,
                                             const float* __restrict__ w_up,
                                             const float* __restrict__ b_up,
                                             float* __restrict__ row) {
    __shared__ float4 mats2[96 * 2];   // per gate: [bit0: m00|m01][bit1: m11|m10]
    __shared__ float  bufR0[BUFSZ], bufI0[BUFSZ], bufR1[BUFSZ], bufI1[BUFSZ];
    __shared__ float  zred[T / 64][NQ];
    __shared__ float  zfin[NQ];

    const int tid  = threadIdx.x;
    const int lane = tid & 63;

    if (tid < 96) {
        const float phi = qw[tid * 3 + 0], theta = qw[tid * 3 + 1], omega = qw[tid * 3 + 2];
        float c, s, sp, cp, sm, cm;
        sincosf(0.5f * theta, &s, &c);
        sincosf(0.5f * (phi + omega), &sp, &cp);
        sincosf(0.5f * (phi - omega), &sm, &cm);
        // m00=(cp*c,-sp*c) m01=(-cm*s,-sm*s) m10=(cm*s,-sm*s) m11=(cp*c,sp*c)
        mats2[tid * 2 + 0] = make_float4(cp * c, -sp * c, -cm * s, -sm * s); // m00|m01
        mats2[tid * 2 + 1] = make_float4(cp * c,  sp * c,  cm * s, -sm * s); // m11|m10
    }
    __syncthreads();

    float2 amp[16];
#pragma unroll
    for (int c = 0; c < 16; ++c) amp[c] = make_float2(0.f, 0.f);
    if (tid == 0) amp[0] = make_float2(1.f, 0.f);

#pragma unroll 1
    for (int l = 0; l < QDEPTH; ++l) {
        const float4* G = &mats2[l * NQ * 2];
        // wires 8-11: c bits 3..0, in-register
        reg_gate(amp, 8, G[16], G[17]);
        reg_gate(amp, 4, G[18], G[19]);
        reg_gate(amp, 2, G[20], G[21]);
        reg_gate(amp, 1, G[22], G[23]);
        // wires 2-7: lane bits 5..0 (mask = 1 << (7 - wire))
        lane_gate<32>(amp, G[4  + ((lane >> 5) & 1)]);
        lane_gate<16>(amp, G[6  + ((lane >> 4) & 1)]);
        lane_gate<8 >(amp, G[8  + ((lane >> 3) & 1)]);
        lane_gate<4 >(amp, G[10 + ((lane >> 2) & 1)]);
        lane_gate<2 >(amp, G[12 + ((lane >> 1) & 1)]);
        lane_gate<1 >(amp, G[14 + ( lane       & 1)]);
        // wires 0-1: wave bits, LDS exchange (ping-pong; 1 barrier each)
        xchg_gate(amp, bufR0, bufI0, tid, 64,  G[2 + ((tid >> 6) & 1)]);
        xchg_gate(amp, bufR1, bufI1, tid, 128, G[0 + ((tid >> 7) & 1)]);
        // CZ entangler diagonal (dropped for last layer: diagonal before measurement)
        if (l < QDEPTH - 1) {
            const int r = l + 1;
#pragma unroll
            for (int c = 0; c < 16; ++c) {
                const unsigned i  = (unsigned)((tid << 4) | c);
                const unsigned ro = ((i << r) | (i >> (12 - r))) & 0xFFFu;
                if (__popc(i & ro) & 1) { amp[c].x = -amp[c].x; amp[c].y = -amp[c].y; }
            }
        }
    }

    // <Z_w>: final amps in regs, i = tid<<4 | c
    float zp[NQ];
#pragma unroll
    for (int w = 0; w < NQ; ++w) zp[w] = 0.0f;
#pragma unroll
    for (int c = 0; c < 16; ++c) {
        const int i = (tid << 4) | c;
        const float pr = amp[c].x * amp[c].x + amp[c].y * amp[c].y;
#pragma unroll
        for (int w = 0; w < NQ; ++w) zp[w] += ((i >> (11 - w)) & 1) ? -pr : pr;
    }
#pragma unroll
    for (int w = 0; w < NQ; ++w) {
        float v = zp[w];
        for (int off = 32; off > 0; off >>= 1) v += __shfl_down(v, off, 64);
        zp[w] = v;
    }
    const int wave = tid >> 6, ln = tid & 63;
    if (ln == 0) {
#pragma unroll
        for (int w = 0; w < NQ; ++w) zred[wave][w] = zp[w];
    }
    __syncthreads();
    if (tid < NQ) {
        float v = 0.0f;
#pragma unroll
        for (int k = 0; k < T / 64; ++k) v += zred[k][tid];
        zfin[tid] = v;
    }
    __syncthreads();

    for (int i = tid; i < 784; i += T) {
        float acc = b_up[i];
#pragma unroll
        for (int j = 0; j < NQ; ++j) acc += zfin[j] * w_up[i * NQ + j];
        row[i] = acc;
    }
}

__global__ __launch_bounds__(256) void qnn_bcast(const float* __restrict__ row,
                                                 float* __restrict__ out) {
    const int t = threadIdx.x;
    if (t < 196) {
        const float4 v = ((const float4*)row)[t];
        ((float4*)out)[(size_t)blockIdx.x * 196 + t] = v;
    }
}

extern "C" void kernel_launch(void* const* d_in, const int* in_sizes, int n_in,
                              void* d_out, int out_size, void* d_ws, size_t ws_size,
                              hipStream_t stream) {
    // inputs: 0:x 1:w_down 2:b_down 3:w_up 4:b_up 5:qweights
    const float* w_up = (const float*)d_in[3];
    const float* b_up = (const float*)d_in[4];
    const float* qw   = (const float*)d_in[5];
    float* row = (float*)d_ws;
    float* out = (float*)d_out;

    qnn_sim<<<1, T, 0, stream>>>(qw, w_up, b_up, row);
    qnn_bcast<<<2048, 256, 0, stream>>>(row, out);
}